// Round 2
// baseline (159.236 us; speedup 1.0000x reference)
//
#include <hip/hip_runtime.h>

#define N_   1024
#define E_   2048
#define W_   (2 * E_ + N_)   // 5120 columns
#define SIG_ 64
#define ROWS_ (N_ + 2 * E_)  // 5120 rows

// Block decomposition (256 threads each, 1 thread = 8 f32 outputs except transpose):
//   [0, TB_)                 : 64x64 LDS-tiled transpose blocks for -M^T   (512)
//   [TB_, TB_+AB_)           : region A rows 0..N      [M | 0 | 0]         (2560)
//   [.., +BB_)               : region B-left rows N..N+E, cols 0..2E [0|I] (4096)
//   [.., +CB_)               : region C rows N+E..     [diag z|diag y|0]   (5120)
#define TB_  ((E_ / 64) * (N_ / 64))      // 32 * 16 = 512
#define AB_  ((N_ * (W_ / 8)) / 256)      // 2560
#define BB_  ((E_ * (2 * E_ / 8)) / 256)  // 4096
#define CB_  ((E_ * (W_ / 8)) / 256)      // 5120

typedef float vf4 __attribute__((ext_vector_type(4)));

union V8 {
    float f[8];
    vf4   q[2];
};

__global__ __launch_bounds__(256) void coeff_kernel(
    const float* __restrict__ M,        // [N_, E_] f32
    const float* __restrict__ params,   // [E_] f32
    const float* __restrict__ sw,       // [E_, SIG_] f32
    const int*   __restrict__ kinds,    // [E_] i32
    const int*   __restrict__ time_p,   // scalar (int payload or float bits)
    float*       __restrict__ out)      // [ROWS_, W_] f32
{
    const int bid = blockIdx.x;
    const int tid = threadIdx.x;

    __shared__ float tile[64][65];   // +1 pad: 2-way max bank aliasing (free)

    if (bid < TB_) {
        // ---- -M^T transpose: out[N_+e][2E_+n] = -M[n][e], 64x64 tile ----
        const int e0 = (bid & 31) << 6;   // 0..2047 step 64
        const int n0 = (bid >> 5) << 6;   // 0..1023 step 64
        const int c4 = (tid & 15) << 2;   // 0..60 step 4
        const int r0 = tid >> 4;          // 0..15
#pragma unroll
        for (int k = 0; k < 4; ++k) {
            const int r = r0 + 16 * k;    // 0..63
            const vf4 m = *reinterpret_cast<const vf4*>(
                M + (size_t)(n0 + r) * E_ + e0 + c4);
            tile[r][c4 + 0] = m.x;
            tile[r][c4 + 1] = m.y;
            tile[r][c4 + 2] = m.z;
            tile[r][c4 + 3] = m.w;
        }
        __syncthreads();
#pragma unroll
        for (int k = 0; k < 4; ++k) {
            const int er = r0 + 16 * k;   // row within e-tile
            vf4 s;
            s.x = -tile[c4 + 0][er];
            s.y = -tile[c4 + 1][er];
            s.z = -tile[c4 + 2][er];
            s.w = -tile[c4 + 3][er];
            float* dst = out + (size_t)(N_ + e0 + er) * W_ + 2 * E_ + n0 + c4;
            __builtin_nontemporal_store(s, reinterpret_cast<vf4*>(dst));
        }
        return;
    }

    V8 v;
#pragma unroll
    for (int j = 0; j < 8; ++j) v.f[j] = 0.0f;

    int row, c0;

    if (bid < TB_ + AB_) {
        // ---- region A: [M | 0 | 0] ----
        const int u = (bid - TB_) * 256 + tid;
        row = u / 640;                    // 640 units per row
        c0  = (u - row * 640) * 8;
        if (c0 < E_) {
            v.q[0] = *reinterpret_cast<const vf4*>(M + (size_t)row * E_ + c0);
            v.q[1] = *reinterpret_cast<const vf4*>(M + (size_t)row * E_ + c0 + 4);
        }
    } else if (bid < TB_ + AB_ + BB_) {
        // ---- region B-left: [0 | I] (cols 0..2E_) ----
        const int u = (bid - TB_ - AB_) * 256 + tid;
        const int e = u >> 9;             // 512 units per row
        c0  = (u & 511) * 8;
        row = N_ + e;
        const int d = (E_ + e) - c0;      // identity at col E_+e
        if (d >= 0 && d < 8) v.f[d] = 1.0f;
    } else {
        // ---- region C: [diag z | diag y | 0] ----
        const int u = (bid - TB_ - AB_ - BB_) * 256 + tid;
        const int e = u / 640;
        c0  = (u - e * 640) * 8;
        row = N_ + E_ + e;
        const int dz = e - c0;
        const int dy = (E_ + e) - c0;
        const bool hz = (dz >= 0) && (dz < 8);
        const bool hy = (dy >= 0) && (dy < 8);
        if (hz || hy) {
            const int   kind = kinds[e];
            const float p    = params[e];

            // robust time read: accept int32 payload or float32 bit pattern
            int t = *time_p;
            if ((unsigned)t >= (unsigned)SIG_) {
                union { int i; float f; } tu; tu.i = t;
                t = (int)tu.f;
                if ((unsigned)t >= (unsigned)SIG_) t = 0;
            }
            const bool  sw_on = sw[e * SIG_ + t] > 0.0f;  // sigmoid(x)>0.5 <=> x>0
            const float ndt   = -1e-6f / p;
            float z, y;
            switch (kind) {
                case 0:  z = -p;                  y = 1.0f;                break; // R
                case 1:  z = 0.0f;                y = 1.0f;                break; // IVS
                case 2:  z = 1.0f;                y = 0.0f;                break; // VC
                case 3:  z = sw_on ? 0.0f : 1.0f; y = sw_on ? 1.0f : 0.0f; break; // SW
                case 4:  z = ndt;                 y = 1.0f;                break; // C
                default: z = 1.0f;                y = ndt;                 break; // L
            }
            if (hz) v.f[dz] = z;
            if (hy) v.f[dy] = y;
        }
    }

    float* dst = out + (size_t)row * W_ + c0;
    __builtin_nontemporal_store(v.q[0], reinterpret_cast<vf4*>(dst));
    __builtin_nontemporal_store(v.q[1], reinterpret_cast<vf4*>(dst + 4));
}

extern "C" void kernel_launch(void* const* d_in, const int* in_sizes, int n_in,
                              void* d_out, int out_size, void* d_ws, size_t ws_size,
                              hipStream_t stream) {
    const float* M      = (const float*)d_in[0];
    const float* params = (const float*)d_in[1];
    const float* sw     = (const float*)d_in[2];
    const int*   kinds  = (const int*)d_in[3];
    const int*   time_p = (const int*)d_in[4];
    float* out          = (float*)d_out;

    const int grid  = TB_ + AB_ + BB_ + CB_;   // 12288
    const int block = 256;
    coeff_kernel<<<grid, block, 0, stream>>>(M, params, sw, kinds, time_p, out);
}